// Round 6
// baseline (247.035 us; speedup 1.0000x reference)
//
#include <hip/hip_runtime.h>

#define BB 64
#define SS 512
#define HH 768
#define EE 128
#define TT 4
#define H4 (HH / 4)        // 192 float4 lanes per row
#define NP (EE * TT)       // 512 (entity,token) pairs
#define NEBLK (SS * 4)     // 2048 enhance blocks: (s, b-group), 16 rows each
#define NGBLK (EE * 4)     // 512 gather blocks: (e, b-group), 16 tasks each
#define CH4 ((size_t)(4 * SS * H4))  // float4 stride for b += 4 in hidden/enhanced
#define CG4 ((size_t)(4 * EE * H4))  // float4 stride for b += 4 in ee

// ---------------------------------------------------------------------------
// Single resident-grid kernel: 2560 blocks x 192 thr = exactly 10 blocks/CU,
// all co-resident (fill-kernel structure -> no dispatch churn, no cold-start
// per unit of work). Block k < 2048: enhance rows {(b0+4i)*S+s, i=0..15} with
// s = k&511, b0 = k>>9 -- all 16 rows SHARE one bucket, so the per-block
// match scan (replaces the old build_index dispatch) is amortized 16x.
// 4-row chunks, ping-pong prefetch (next 4 loads in flight under current
// correction+store). Blocks >= 2048: ee[b,e,:] analytically from hidden +
// the entity's 4 token buckets (same e for 16 tasks -> scan amortized 16x),
// depth-2 pipeline; reads are L3 hits.
// ---------------------------------------------------------------------------
__global__ __launch_bounds__(H4) void fused_kernel(
    const float* __restrict__ hidden,
    const int* __restrict__ entity_types,   // (B,E)
    const float* __restrict__ conf,         // (B,E)
    const int* __restrict__ ent_tokens,     // (E,T)
    const float* __restrict__ type_table,   // (5,H)
    const float* __restrict__ conf_w,       // (H)
    const float* __restrict__ conf_b,       // (H)
    float* __restrict__ enhanced,           // (B,S,H)
    float* __restrict__ ee) {               // (B,E,H)
  const int tid = threadIdx.x;  // 0..191
  const int blk = blockIdx.x;

  __shared__ int nmatch;
  __shared__ int mlist[NP];
  if (tid == 0) nmatch = 0;
  __syncthreads();

  const float4* tt4 = (const float4*)type_table;
  const float4* hp = (const float4*)hidden;
  const float4 wv = ((const float4*)conf_w)[tid];
  const float4 bv = ((const float4*)conf_b)[tid];

  if (blk < NEBLK) {
    // ------------------------- enhance path -------------------------------
    const int s = blk & (SS - 1);
    const int b0 = blk >> 9;  // 0..3

    for (int p = tid; p < NP; p += H4)
      if (ent_tokens[p] == s) mlist[atomicAdd(&nmatch, 1)] = p >> 2;
    __syncthreads();
    const int n = nmatch;

    const size_t base = ((size_t)(b0 * SS + s)) * H4 + tid;
    float4* outp = (float4*)enhanced;

    auto proc = [&](float4 v, int bi) {
      if (n > 0) {
        const int b = b0 + 4 * bi;
        float4 ts = make_float4(0.f, 0.f, 0.f, 0.f);
        float cs = 0.f;
        for (int j = 0; j < n; ++j) {
          const int e = mlist[j];  // LDS broadcast
          cs += conf[b * EE + e];
          const float4 tv = tt4[entity_types[b * EE + e] * H4 + tid];
          ts.x += tv.x;
          ts.y += tv.y;
          ts.z += tv.z;
          ts.w += tv.w;
        }
        const float fn = (float)n;
        v.x += ts.x + fmaf(cs, wv.x, fn * bv.x);
        v.y += ts.y + fmaf(cs, wv.y, fn * bv.y);
        v.z += ts.z + fmaf(cs, wv.z, fn * bv.z);
        v.w += ts.w + fmaf(cs, wv.w, fn * bv.w);
      }
      outp[base + (size_t)bi * CH4] = v;
    };

    // chunk 0 + chunk 1 loads in flight
    float4 a0 = hp[base + 0 * CH4], a1 = hp[base + 1 * CH4];
    float4 a2 = hp[base + 2 * CH4], a3 = hp[base + 3 * CH4];
    float4 q0 = hp[base + 4 * CH4], q1 = hp[base + 5 * CH4];
    float4 q2 = hp[base + 6 * CH4], q3 = hp[base + 7 * CH4];
    proc(a0, 0); proc(a1, 1); proc(a2, 2); proc(a3, 3);
    a0 = hp[base + 8 * CH4];  a1 = hp[base + 9 * CH4];
    a2 = hp[base + 10 * CH4]; a3 = hp[base + 11 * CH4];
    proc(q0, 4); proc(q1, 5); proc(q2, 6); proc(q3, 7);
    q0 = hp[base + 12 * CH4]; q1 = hp[base + 13 * CH4];
    q2 = hp[base + 14 * CH4]; q3 = hp[base + 15 * CH4];
    proc(a0, 8); proc(a1, 9); proc(a2, 10); proc(a3, 11);
    proc(q0, 12); proc(q1, 13); proc(q2, 14); proc(q3, 15);
  } else {
    // ------------------------ gather/mean path ----------------------------
    const int g = blk - NEBLK;
    const int e = g & (EE - 1);
    const int b0 = g >> 7;  // 0..3

    const int s0 = ent_tokens[e * TT + 0];
    const int s1 = ent_tokens[e * TT + 1];
    const int s2 = ent_tokens[e * TT + 2];
    const int s3 = ent_tokens[e * TT + 3];

    for (int p = tid; p < NP; p += H4) {
      const int tok = ent_tokens[p];
      const int w = (tok == s0) + (tok == s1) + (tok == s2) + (tok == s3);
      if (w) mlist[atomicAdd(&nmatch, 1)] = (p >> 2) | (w << 16);
    }
    __syncthreads();
    const int n = nmatch;

    const size_t h0 = ((size_t)(b0 * SS + s0)) * H4 + tid;
    const size_t h1 = ((size_t)(b0 * SS + s1)) * H4 + tid;
    const size_t h2 = ((size_t)(b0 * SS + s2)) * H4 + tid;
    const size_t h3 = ((size_t)(b0 * SS + s3)) * H4 + tid;
    const size_t ob = ((size_t)(b0 * EE + e)) * H4 + tid;
    float4* eep = (float4*)ee;

    auto proc = [&](float4 v0, float4 v1, float4 v2, float4 v3, int bi) {
      const int b = b0 + 4 * bi;
      float4 ts = make_float4(0.f, 0.f, 0.f, 0.f);
      float cs = 0.f, ws = 0.f;
      for (int j = 0; j < n; ++j) {
        const int pk = mlist[j];
        const int e2 = pk & 0xffff;
        const float fw = (float)(pk >> 16);
        cs += fw * conf[b * EE + e2];
        ws += fw;
        const float4 tv = tt4[entity_types[b * EE + e2] * H4 + tid];
        ts.x += fw * tv.x;
        ts.y += fw * tv.y;
        ts.z += fw * tv.z;
        ts.w += fw * tv.w;
      }
      float4 o;
      o.x = 0.25f * ((v0.x + v1.x) + (v2.x + v3.x) + ts.x + fmaf(cs, wv.x, ws * bv.x));
      o.y = 0.25f * ((v0.y + v1.y) + (v2.y + v3.y) + ts.y + fmaf(cs, wv.y, ws * bv.y));
      o.z = 0.25f * ((v0.z + v1.z) + (v2.z + v3.z) + ts.z + fmaf(cs, wv.z, ws * bv.z));
      o.w = 0.25f * ((v0.w + v1.w) + (v2.w + v3.w) + ts.w + fmaf(cs, wv.w, ws * bv.w));
      eep[ob + (size_t)bi * CG4] = o;
    };

    float4 a0 = hp[h0], a1 = hp[h1], a2 = hp[h2], a3 = hp[h3];
#pragma unroll
    for (int i = 0; i < 16; i += 2) {
      const float4 c0 = hp[h0 + (size_t)(i + 1) * CH4];
      const float4 c1 = hp[h1 + (size_t)(i + 1) * CH4];
      const float4 c2 = hp[h2 + (size_t)(i + 1) * CH4];
      const float4 c3 = hp[h3 + (size_t)(i + 1) * CH4];
      proc(a0, a1, a2, a3, i);
      if (i + 2 < 16) {
        a0 = hp[h0 + (size_t)(i + 2) * CH4];
        a1 = hp[h1 + (size_t)(i + 2) * CH4];
        a2 = hp[h2 + (size_t)(i + 2) * CH4];
        a3 = hp[h3 + (size_t)(i + 2) * CH4];
      }
      proc(c0, c1, c2, c3, i + 1);
    }
  }
}

extern "C" void kernel_launch(void* const* d_in, const int* in_sizes, int n_in,
                              void* d_out, int out_size, void* d_ws,
                              size_t ws_size, hipStream_t stream) {
  const float* hidden = (const float*)d_in[0];      // (B,S,H) fp32
  const int* entity_types = (const int*)d_in[1];    // (B,E) i32
  const float* conf = (const float*)d_in[2];        // (B,E) fp32
  const int* ent_tokens = (const int*)d_in[3];      // (E,T) i32
  const float* type_table = (const float*)d_in[4];  // (5,H) fp32
  const float* conf_w = (const float*)d_in[5];      // (1,H) fp32
  const float* conf_b = (const float*)d_in[6];      // (H) fp32

  float* enhanced = (float*)d_out;                   // (B,S,H)
  float* ee = (float*)d_out + (size_t)BB * SS * HH;  // (B,E,H)

  fused_kernel<<<NEBLK + NGBLK, H4, 0, stream>>>(
      hidden, entity_types, conf, ent_tokens, type_table, conf_w, conf_b,
      enhanced, ee);
}

// Round 7
// 228.695 us; speedup vs baseline: 1.0802x; 1.0802x over previous
//
#include <hip/hip_runtime.h>

#define BB 64
#define SS 512
#define HH 768
#define EE 128
#define TT 4
#define H4 (HH / 4)      // 192 float4 lanes per row
#define NP (EE * TT)     // 512 (entity,token) pairs
#define NROWS (BB * SS)  // 32768 enhance rows
#define NEBLK (NROWS / 8)  // 4096 enhance blocks (8 contiguous rows each)
#define NGBLK (BB * EE / 2)  // 4096 gather blocks (2 tasks: b and b+32)

// ---------------------------------------------------------------------------
// Kernel A: counting-sort ent_tokens (512 pairs) by token position s.
// offsets[S+1], entries[512] (entity per pair; duplicates preserved).
// One block, 512 threads, ~4 us. Rebuilt every launch (d_ws re-poisoned).
// ---------------------------------------------------------------------------
__global__ __launch_bounds__(SS) void build_index_kernel(
    const int* __restrict__ ent_tokens,
    int* __restrict__ offsets,    // S+1 ints
    int* __restrict__ entries) {  // E*T ints
  __shared__ int cnt[SS];
  __shared__ int scan[SS];
  __shared__ int pos[SS];
  const int tid = threadIdx.x;  // 0..511

  cnt[tid] = 0;
  __syncthreads();

  const int s = ent_tokens[tid];
  atomicAdd(&cnt[s], 1);
  __syncthreads();

  scan[tid] = cnt[tid];
  __syncthreads();
  for (int off = 1; off < SS; off <<= 1) {
    int add = (tid >= off) ? scan[tid - off] : 0;
    __syncthreads();
    scan[tid] += add;
    __syncthreads();
  }

  const int excl = scan[tid] - cnt[tid];
  offsets[tid] = excl;
  if (tid == 0) offsets[SS] = NP;
  pos[tid] = excl;
  __syncthreads();

  const int p = atomicAdd(&pos[s], 1);
  entries[p] = tid >> 2;  // e = pair / T
}

// ---------------------------------------------------------------------------
// Kernel B: one dispatch, parity-interleaved roles so enhance and gather are
// co-resident for the whole run (kills the r5 dispatch-order tail).
//   Even blocks: enhance 8 CONSECUTIVE rows (same b): 8 independent 3 KB
//     loads in flight (24 KB contiguous span), per-row bucket correction via
//     offsets/entries (scalar, L1-hot), 8 stores.
//   Odd blocks: 2 gather tasks (same e, b and b+32): ee[b,e,:] analytically
//     from hidden + the entity's 4 token buckets -- no dependency on the
//     enhance output; 8 independent loads in flight, mostly L3 hits.
// ---------------------------------------------------------------------------
__global__ __launch_bounds__(H4) void fused_kernel(
    const float* __restrict__ hidden,
    const int* __restrict__ entity_types,   // (B,E)
    const float* __restrict__ conf,         // (B,E)
    const int* __restrict__ ent_tokens,     // (E,T)
    const float* __restrict__ type_table,   // (5,H)
    const float* __restrict__ conf_w,       // (H)
    const float* __restrict__ conf_b,       // (H)
    const int* __restrict__ offsets,
    const int* __restrict__ entries,
    float* __restrict__ enhanced,           // (B,S,H)
    float* __restrict__ ee) {               // (B,E,H)
  const int tid = threadIdx.x;  // 0..191
  const int blk = blockIdx.x;
  const float4* tt4 = (const float4*)type_table;
  const float4* hp = (const float4*)hidden;
  const float4 wv = ((const float4*)conf_w)[tid];
  const float4 bv = ((const float4*)conf_b)[tid];

  if ((blk & 1) == 0) {
    // ------------------------- enhance path (8 rows) ----------------------
    const int row0 = (blk >> 1) << 3;  // 8-aligned => all rows share b
    const int b = row0 >> 9;           // / SS
    const int s0 = row0 & (SS - 1);
    const size_t base = (size_t)row0 * H4 + tid;

    // 8 independent loads in flight (24 KB contiguous span per block)
    float4 vr[8];
#pragma unroll
    for (int i = 0; i < 8; ++i) vr[i] = hp[base + (size_t)i * H4];

    int off[9];
#pragma unroll
    for (int i = 0; i < 9; ++i) off[i] = offsets[s0 + i];

    const int* etb = entity_types + b * EE;
    const float* cfb = conf + b * EE;
#pragma unroll
    for (int i = 0; i < 8; ++i) {
      const int o0 = off[i];
      const int o1 = off[i + 1];
      if (o1 > o0) {
        float4 ts = make_float4(0.f, 0.f, 0.f, 0.f);
        float cs = 0.f;
        for (int j = o0; j < o1; ++j) {
          const int e = entries[j];
          cs += cfb[e];
          const float4 tv = tt4[etb[e] * H4 + tid];
          ts.x += tv.x;
          ts.y += tv.y;
          ts.z += tv.z;
          ts.w += tv.w;
        }
        const float fn = (float)(o1 - o0);
        vr[i].x += ts.x + fmaf(cs, wv.x, fn * bv.x);
        vr[i].y += ts.y + fmaf(cs, wv.y, fn * bv.y);
        vr[i].z += ts.z + fmaf(cs, wv.z, fn * bv.z);
        vr[i].w += ts.w + fmaf(cs, wv.w, fn * bv.w);
      }
    }

    float4* outp = (float4*)enhanced;
#pragma unroll
    for (int i = 0; i < 8; ++i) outp[base + (size_t)i * H4] = vr[i];
  } else {
    // --------------------- gather/mean path (2 tasks) ---------------------
    const int g = blk >> 1;          // 0..4095
    const int e = g & (EE - 1);
    const int bA = g >> 7;           // 0..31
    const int bB = bA + 32;

    const int s0 = ent_tokens[e * TT + 0];
    const int s1 = ent_tokens[e * TT + 1];
    const int s2 = ent_tokens[e * TT + 2];
    const int s3 = ent_tokens[e * TT + 3];

    // 8 independent loads in flight (mostly L3 hits)
    const float4* hA = hp + (size_t)bA * SS * H4;
    const float4* hB = hp + (size_t)bB * SS * H4;
    const float4 a0 = hA[(size_t)s0 * H4 + tid];
    const float4 a1 = hA[(size_t)s1 * H4 + tid];
    const float4 a2 = hA[(size_t)s2 * H4 + tid];
    const float4 a3 = hA[(size_t)s3 * H4 + tid];
    const float4 c0 = hB[(size_t)s0 * H4 + tid];
    const float4 c1 = hB[(size_t)s1 * H4 + tid];
    const float4 c2 = hB[(size_t)s2 * H4 + tid];
    const float4 c3 = hB[(size_t)s3 * H4 + tid];

    int oo[8];
    oo[0] = offsets[s0]; oo[1] = offsets[s0 + 1];
    oo[2] = offsets[s1]; oo[3] = offsets[s1 + 1];
    oo[4] = offsets[s2]; oo[5] = offsets[s2 + 1];
    oo[6] = offsets[s3]; oo[7] = offsets[s3 + 1];

    float4* eep = (float4*)ee;
#pragma unroll
    for (int task = 0; task < 2; ++task) {
      const int b = (task == 0) ? bA : bB;
      float4 ts = make_float4(0.f, 0.f, 0.f, 0.f);
      float cs = 0.f;
      float ws = 0.f;
      const int* etb = entity_types + b * EE;
      const float* cfb = conf + b * EE;
      // buckets of the 4 tokens reproduce exactly the pairs summed into the
      // 4 enhanced rows (duplicates included)
#pragma unroll
      for (int t = 0; t < TT; ++t) {
        const int j0 = oo[2 * t];
        const int j1 = oo[2 * t + 1];
        for (int j = j0; j < j1; ++j) {
          const int e2 = entries[j];
          cs += cfb[e2];
          ws += 1.f;
          const float4 tv = tt4[etb[e2] * H4 + tid];
          ts.x += tv.x;
          ts.y += tv.y;
          ts.z += tv.z;
          ts.w += tv.w;
        }
      }
      float4 acc;
      if (task == 0) {
        acc.x = (a0.x + a1.x) + (a2.x + a3.x);
        acc.y = (a0.y + a1.y) + (a2.y + a3.y);
        acc.z = (a0.z + a1.z) + (a2.z + a3.z);
        acc.w = (a0.w + a1.w) + (a2.w + a3.w);
      } else {
        acc.x = (c0.x + c1.x) + (c2.x + c3.x);
        acc.y = (c0.y + c1.y) + (c2.y + c3.y);
        acc.z = (c0.z + c1.z) + (c2.z + c3.z);
        acc.w = (c0.w + c1.w) + (c2.w + c3.w);
      }
      float4 o;
      o.x = 0.25f * (acc.x + ts.x + fmaf(cs, wv.x, ws * bv.x));
      o.y = 0.25f * (acc.y + ts.y + fmaf(cs, wv.y, ws * bv.y));
      o.z = 0.25f * (acc.z + ts.z + fmaf(cs, wv.z, ws * bv.z));
      o.w = 0.25f * (acc.w + ts.w + fmaf(cs, wv.w, ws * bv.w));
      eep[(size_t)(b * EE + e) * H4 + tid] = o;
    }
  }
}

extern "C" void kernel_launch(void* const* d_in, const int* in_sizes, int n_in,
                              void* d_out, int out_size, void* d_ws,
                              size_t ws_size, hipStream_t stream) {
  const float* hidden = (const float*)d_in[0];      // (B,S,H) fp32
  const int* entity_types = (const int*)d_in[1];    // (B,E) i32
  const float* conf = (const float*)d_in[2];        // (B,E) fp32
  const int* ent_tokens = (const int*)d_in[3];      // (E,T) i32
  const float* type_table = (const float*)d_in[4];  // (5,H) fp32
  const float* conf_w = (const float*)d_in[5];      // (1,H) fp32
  const float* conf_b = (const float*)d_in[6];      // (H) fp32

  float* enhanced = (float*)d_out;                   // (B,S,H)
  float* ee = (float*)d_out + (size_t)BB * SS * HH;  // (B,E,H)

  int* offsets = (int*)d_ws;          // S+1
  int* entries = offsets + (SS + 1);  // E*T

  build_index_kernel<<<1, SS, 0, stream>>>(ent_tokens, offsets, entries);
  fused_kernel<<<NEBLK + NGBLK, H4, 0, stream>>>(
      hidden, entity_types, conf, ent_tokens, type_table, conf_w, conf_b,
      offsets, entries, enhanced, ee);
}